// Round 27
// baseline (153.028 us; speedup 1.0000x reference)
//
#include <hip/hip_runtime.h>
#include <hip/hip_bf16.h>

#define BB 32
#define NN 1024
#define WW 64
#define RR 4
#define IFD 471
#define OUTD 256
#define EPS 1e-6f

typedef float f4 __attribute__((ext_vector_type(4)));

// ---------- ws layout (floats) ----------
#define WS_PARAMS 0
#define WS_SIMW   16384
#define WS_SIMR   49152
#define WS_FW     180224
#define WS_BW     311296

// params per-batch layout:
// 0:write_key[64] 64:write_vec[64] 128:erase[64] 192:free[4] 196:rstr[4]
// 200:wstr 201:wg 202:ag 203:key_norm 204:rk_norm[4] 208:mode[3][4]
// 224:read_keys[w][r] (256)

__device__ __forceinline__ float sigmoidf_(float x){ return 1.f/(1.f+expf(-x)); }
__device__ __forceinline__ float softplusf_(float x){ return fmaxf(x,0.f)+log1pf(expf(-fabsf(x))); }

// fused head: parse + usage/simw + sort/alloc + write softmax + write_w +
// precedence_new, one block per batch. Also zeros fw/bw accumulators.
__global__ __launch_bounds__(1024) void k_head(
    const float* __restrict__ itf, const float* __restrict__ mem,
    const float* __restrict__ rwts, const float* __restrict__ wwts,
    const float* __restrict__ usage_in, const float* __restrict__ prec,
    float* __restrict__ P, float* __restrict__ write_w_out,
    float* __restrict__ prec_new_out, float* __restrict__ usage_out,
    float* __restrict__ fwbw_zero){
  __shared__ float sp[512];
  __shared__ float su[1024], sv[1024], sred[1024], ssimw[1024];
  __shared__ int sidx[1024];
  int t = threadIdx.x, b = blockIdx.x;
  int lane = t & 63, wg = t >> 6;
  {
    float* z = fwbw_zero + b*8192;
    #pragma unroll
    for (int i=0;i<8;++i) z[i*1024 + t] = 0.f;
  }
  const float* x = itf + b*IFD;
  if (t < 64){
    sp[t]      = x[t];
    sp[64+t]   = x[64+t];
    sp[128+t]  = sigmoidf_(x[128+t]);
    float wk = x[t];
    float k2 = wk*wk;
    for (int m=32;m;m>>=1) k2 += __shfl_xor(k2, m);
    if (t == 0) sp[203] = sqrtf(k2);
  }
  if (t < 4){
    sp[192+t] = sigmoidf_(x[192+t]);
    sp[196+t] = 1.f + softplusf_(x[196+t]);
  }
  if (t == 0){
    sp[200] = 1.f + softplusf_(x[200]);
    sp[201] = sigmoidf_(x[201]);
    sp[202] = sigmoidf_(x[202]);
  }
  if (t < 256){
    int w = t & 63, r = t >> 6;
    float rk = x[203 + r*64 + w];
    sp[224 + w*4 + r] = rk;
    float s2 = rk*rk;
    for (int m=32;m;m>>=1) s2 += __shfl_xor(s2, m);
    if (w == 0) sp[204 + r] = sqrtf(s2);
  }
  if (t < 4){
    float a0=x[459+t*3+0], a1=x[459+t*3+1], a2=x[459+t*3+2];
    float mx = fmaxf(a0, fmaxf(a1,a2));
    float e0=expf(a0-mx), e1=expf(a1-mx), e2=expf(a2-mx);
    float s = e0+e1+e2;
    sp[208 + 0*4 + t] = e0/s;
    sp[208 + 1*4 + t] = e1/s;
    sp[208 + 2*4 + t] = e2/s;
  }
  __syncthreads();
  if (t < 512) P[b*512 + t] = sp[t];
  {
    const size_t base = (size_t)b*NN;
    int q = lane & 15, rs = lane >> 4;
    f4 wk4 = *(const f4*)(sp + q*4);
    float keyn = sp[203], wstr = sp[200];
    float g0=sp[192], g1=sp[193], g2=sp[194], g3=sp[195];
    #pragma unroll 4
    for (int it=0; it<16; ++it){
      int row = wg*64 + it*4 + rs;
      f4 m4 = *(const f4*)(mem + (base+row)*64 + q*4);
      float s2 = m4.x*m4.x + m4.y*m4.y + m4.z*m4.z + m4.w*m4.w;
      float sd = m4.x*wk4.x + m4.y*wk4.y + m4.z*wk4.z + m4.w*wk4.w;
      s2 += __shfl_xor(s2,1); sd += __shfl_xor(sd,1);
      s2 += __shfl_xor(s2,2); sd += __shfl_xor(sd,2);
      s2 += __shfl_xor(s2,4); sd += __shfl_xor(sd,4);
      s2 += __shfl_xor(s2,8); sd += __shfl_xor(sd,8);
      if (q == 0){
        ssimw[row] = sd / (sqrtf(s2)*keyn + EPS) * wstr;
        f4 r4 = *(const f4*)(rwts + (base+row)*4);
        float ret = (1.f-g0*r4.x)*(1.f-g1*r4.y)*(1.f-g2*r4.z)*(1.f-g3*r4.w);
        float pu = usage_in[base+row];
        float ww = wwts[base+row];
        float uo = (pu + ww - pu*ww) * ret;
        usage_out[base+row] = uo;
        su[row] = EPS + (1.f-EPS)*uo;
        sidx[row] = row;
      }
    }
  }
  __syncthreads();
  for (int k=2; k<=1024; k<<=1){
    for (int j=k>>1; j; j>>=1){
      int ixj = t ^ j;
      if (ixj > t){
        float a = su[t], c = su[ixj];
        int ia = sidx[t], ic = sidx[ixj];
        bool up = ((t & k) == 0);
        bool gt = (a > c) || (a == c && ia > ic);
        if (gt == up){ su[t]=c; su[ixj]=a; sidx[t]=ic; sidx[ixj]=ia; }
      }
      __syncthreads();
    }
  }
  sv[t] = su[t];
  __syncthreads();
  for (int off=1; off<1024; off<<=1){
    float y = (t >= off) ? su[t-off] : 1.f;
    __syncthreads();
    su[t] *= y;
    __syncthreads();
  }
  float excl = (t == 0) ? 1.f : su[t-1];
  float alloc_sorted = (1.f - sv[t]) * excl;
  sred[sidx[t]] = alloc_sorted;
  __syncthreads();
  float alloc = sred[t];
  float sim = ssimw[t];
  sv[t] = sim; __syncthreads();
  for (int s=512; s; s>>=1){ if (t<s) sv[t] = fmaxf(sv[t], sv[t+s]); __syncthreads(); }
  float mx = sv[0]; __syncthreads();
  float e = expf(sim - mx);
  sv[t] = e; __syncthreads();
  for (int s=512; s; s>>=1){ if (t<s) sv[t] += sv[t+s]; __syncthreads(); }
  float wa = e / sv[0];
  float wg_ = sp[201], ag = sp[202];
  float ww = wg_ * ((1.f-ag)*wa + ag*alloc);
  write_w_out[b*NN + t] = ww;
  __syncthreads();
  sv[t] = ww; __syncthreads();
  for (int s=512; s; s>>=1){ if (t<s) sv[t] += sv[t+s]; __syncthreads(); }
  float S = sv[0];
  prec_new_out[b*NN + t] = (1.f - S)*prec[b*NN + t] + ww;
}

// PASS 1: pure stream, PERFECTLY LINEAR. Thread t owns cols t*4..+3; block B
// covers rows (B&127)*8..+7 full-width. Every wave instruction = 1 KB
// contiguous; each block iteration = one whole 4 KB DRAM row. No LDS, no
// barrier, no atomics. NT store. Clean DRAM-granularity probe.
__global__ __launch_bounds__(256) void k_stream(const float* __restrict__ link,
    const float* __restrict__ prec, const float* __restrict__ write_w,
    float* __restrict__ link_new){
  int t = threadIdx.x;
  int h = blockIdx.x;
  int B = (h & 7)*512 + (h >> 3);       // XCD swizzle (4096 = 8 x 512, bijective)
  int b  = B >> 7;
  int r0 = (B & 127) * 8;
  int c0 = t*4;
  const size_t base = (size_t)b*NN;
  const size_t lbb  = (size_t)b*NN*NN;
  f4 wj = *(const f4*)(write_w + base + c0);
  f4 pj = *(const f4*)(prec + base + c0);
  #pragma unroll
  for (int k=0; k<8; ++k){
    int i = r0 + k;
    float wi = write_w[base + i];       // block-uniform scalar
    f4 L4 = *(const f4*)(link + lbb + (size_t)i*NN + c0);
    float om = 1.f - wi;
    f4 v;
    v.x = fmaf(om + wj.x, L4.x, wi*pj.x);
    v.y = fmaf(om + wj.y, L4.y, wi*pj.y);
    v.z = fmaf(om + wj.z, L4.z, wi*pj.z);
    v.w = fmaf(om + wj.w, L4.w, wi*pj.w);
    v.x = (i == c0  ) ? 0.f : v.x;
    v.y = (i == c0+1) ? 0.f : v.y;
    v.z = (i == c0+2) ? 0.f : v.z;
    v.w = (i == c0+3) ? 0.f : v.w;
    __builtin_nontemporal_store(v, (f4*)(link_new + lbb + (size_t)i*NN + c0));
  }
}

// PASS 2: fw/bw reduction. Re-reads LINK (L3-warm; link_new is NT = L3-cold)
// and recomputes v (2 fma). Champion epilogue: LDS-staged bw, coalesced dense
// atomics; fw shfl+LDS+coalesced atomics; memupd fold (8 rows/block).
__global__ __launch_bounds__(256) void k_fwbw(const float* __restrict__ link,
    const float* __restrict__ rwts, const float* __restrict__ prec,
    const float* __restrict__ write_w, const float* __restrict__ mem,
    const float* __restrict__ P,
    float* __restrict__ fw, float* __restrict__ bw,
    float* __restrict__ mu_out, float* __restrict__ simr){
  __shared__ float red[4352];           // bw stage: (r*64 + col_local)*17 + ty
  __shared__ float sfw[512];            // fw stage: row_local*4 + r
  int t = threadIdx.x;
  int tx = t & 15, ty = t >> 4;
  int h = blockIdx.x;
  int lb = (h & 7)*512 + (h >> 3);
  int b  = lb >> 7;
  int rt = (lb >> 4) & 7;
  int ct = lb & 15;
  int row0 = rt*128 + ty*8;
  int col0 = ct*64 + tx*4;
  const size_t base = (size_t)b*NN;
  const size_t lbb  = (size_t)b*NN*NN;
  f4 wj = *(const f4*)(write_w + base + col0);
  f4 pj = *(const f4*)(prec + base + col0);
  f4 rj0 = *(const f4*)(rwts + (base + col0+0)*4);
  f4 rj1 = *(const f4*)(rwts + (base + col0+1)*4);
  f4 rj2 = *(const f4*)(rwts + (base + col0+2)*4);
  f4 rj3 = *(const f4*)(rwts + (base + col0+3)*4);
  float fwacc[8][4];
  float bwacc[4][4];
  #pragma unroll
  for (int a=0;a<8;++a) for (int c=0;c<4;++c) fwacc[a][c]=0.f;
  #pragma unroll
  for (int a=0;a<4;++a) for (int c=0;c<4;++c) bwacc[a][c]=0.f;
  #pragma unroll
  for (int dr=0; dr<8; ++dr){
    int i = row0 + dr;
    float wi = write_w[base + i];
    f4 ri = *(const f4*)(rwts + (base + i)*4);
    f4 L4 = *(const f4*)(link + lbb + (size_t)i*NN + col0);
    float om = 1.f - wi;
    f4 v;
    v.x = fmaf(om + wj.x, L4.x, wi*pj.x);
    v.y = fmaf(om + wj.y, L4.y, wi*pj.y);
    v.z = fmaf(om + wj.z, L4.z, wi*pj.z);
    v.w = fmaf(om + wj.w, L4.w, wi*pj.w);
    v.x = (i == col0  ) ? 0.f : v.x;
    v.y = (i == col0+1) ? 0.f : v.y;
    v.z = (i == col0+2) ? 0.f : v.z;
    v.w = (i == col0+3) ? 0.f : v.w;
    fwacc[dr][0] += v.x*rj0.x + v.y*rj1.x + v.z*rj2.x + v.w*rj3.x;
    fwacc[dr][1] += v.x*rj0.y + v.y*rj1.y + v.z*rj2.y + v.w*rj3.y;
    fwacc[dr][2] += v.x*rj0.z + v.y*rj1.z + v.z*rj2.z + v.w*rj3.z;
    fwacc[dr][3] += v.x*rj0.w + v.y*rj1.w + v.z*rj2.w + v.w*rj3.w;
    bwacc[0][0] = fmaf(v.x, ri.x, bwacc[0][0]); bwacc[0][1] = fmaf(v.x, ri.y, bwacc[0][1]);
    bwacc[0][2] = fmaf(v.x, ri.z, bwacc[0][2]); bwacc[0][3] = fmaf(v.x, ri.w, bwacc[0][3]);
    bwacc[1][0] = fmaf(v.y, ri.x, bwacc[1][0]); bwacc[1][1] = fmaf(v.y, ri.y, bwacc[1][1]);
    bwacc[1][2] = fmaf(v.y, ri.z, bwacc[1][2]); bwacc[1][3] = fmaf(v.y, ri.w, bwacc[1][3]);
    bwacc[2][0] = fmaf(v.z, ri.x, bwacc[2][0]); bwacc[2][1] = fmaf(v.z, ri.y, bwacc[2][1]);
    bwacc[2][2] = fmaf(v.z, ri.z, bwacc[2][2]); bwacc[2][3] = fmaf(v.z, ri.w, bwacc[2][3]);
    bwacc[3][0] = fmaf(v.w, ri.x, bwacc[3][0]); bwacc[3][1] = fmaf(v.w, ri.y, bwacc[3][1]);
    bwacc[3][2] = fmaf(v.w, ri.z, bwacc[3][2]); bwacc[3][3] = fmaf(v.w, ri.w, bwacc[3][3]);
  }
  #pragma unroll
  for (int dr=0; dr<8; ++dr)
    #pragma unroll
    for (int r=0; r<4; ++r){
      float s = fwacc[dr][r];
      s += __shfl_xor(s,1); s += __shfl_xor(s,2);
      s += __shfl_xor(s,4); s += __shfl_xor(s,8);
      if (tx == 0) sfw[(ty*8+dr)*4 + r] = s;
    }
  #pragma unroll
  for (int dc=0; dc<4; ++dc)
    #pragma unroll
    for (int r=0; r<4; ++r)
      red[(r*64 + tx*4+dc)*17 + ty] = bwacc[dc][r];
  __syncthreads();
  atomicAdd(&fw[(base + rt*128)*4 + t],       sfw[t]);
  atomicAdd(&fw[(base + rt*128)*4 + t + 256], sfw[t + 256]);
  {
    int coll = t >> 2, r = t & 3;
    const float* q = red + (r*64 + coll)*17;
    float s = 0.f;
    #pragma unroll
    for (int i=0; i<16; ++i) s += q[i];
    atomicAdd(&bw[(base + ct*64 + coll)*4 + r], s);
  }
  // distributed memory-update + read-sim: this block's 8 rows
  {
    const float* p = P + b*512;
    int slot = t >> 4;
    int q = t & 15;
    if (slot < 8){
      int row = rt*128 + ct*8 + slot;
      float ww = write_w[base + row];
      f4 er4 = *(const f4*)(p + 128 + q*4);
      f4 wv4 = *(const f4*)(p + 64 + q*4);
      f4 m4 = *(const f4*)(mem + (base+row)*64 + q*4);
      f4 mu;
      mu.x = m4.x*(1.f - ww*er4.x) + ww*wv4.x;
      mu.y = m4.y*(1.f - ww*er4.y) + ww*wv4.y;
      mu.z = m4.z*(1.f - ww*er4.z) + ww*wv4.z;
      mu.w = m4.w*(1.f - ww*er4.w) + ww*wv4.w;
      *(f4*)(mu_out + (base+row)*64 + q*4) = mu;
      f4 rk0 = *(const f4*)(p + 224 + (q*4+0)*4);
      f4 rk1 = *(const f4*)(p + 224 + (q*4+1)*4);
      f4 rk2 = *(const f4*)(p + 224 + (q*4+2)*4);
      f4 rk3 = *(const f4*)(p + 224 + (q*4+3)*4);
      float s2 = mu.x*mu.x + mu.y*mu.y + mu.z*mu.z + mu.w*mu.w;
      f4 d = mu.x*rk0 + mu.y*rk1 + mu.z*rk2 + mu.w*rk3;
      #pragma unroll
      for (int k=1; k<16; k<<=1){
        s2  += __shfl_xor(s2,k);
        d.x += __shfl_xor(d.x,k); d.y += __shfl_xor(d.y,k);
        d.z += __shfl_xor(d.z,k); d.w += __shfl_xor(d.w,k);
      }
      if (q == 0){
        f4 rkn = *(const f4*)(p + 204);
        f4 rst = *(const f4*)(p + 196);
        float norm = sqrtf(s2);
        f4 o;
        o.x = d.x/(norm*rkn.x+EPS)*rst.x;
        o.y = d.y/(norm*rkn.y+EPS)*rst.y;
        o.z = d.z/(norm*rkn.z+EPS)*rst.z;
        o.w = d.w/(norm*rkn.w+EPS)*rst.w;
        *(f4*)(simr + (base+row)*4) = o;
      }
    }
  }
}

// fused tail: per batch, read softmax + combine -> read_w; read_vec; GEMV out.
__global__ __launch_bounds__(1024) void k_tail(
    const float* __restrict__ simr, const float* __restrict__ fw,
    const float* __restrict__ bw, const float* __restrict__ P,
    const float* __restrict__ mu, const float* __restrict__ Wout,
    const float* __restrict__ bout,
    float* __restrict__ readw_out, float* __restrict__ rv_out,
    float* __restrict__ out0){
  __shared__ float srw[4][1024];
  __shared__ float part[4352];
  __shared__ float red[16];
  __shared__ float srv[256];
  int t = threadIdx.x, b = blockIdx.x;
  int lane = t & 63, wid = t >> 6;
  const float* p = P + b*512;
  const size_t base = (size_t)b*NN;
  f4 s4 = *(const f4*)(simr + (base + t)*4);
  f4 f4v = *(const f4*)(fw + (base + t)*4);
  f4 b4v = *(const f4*)(bw + (base + t)*4);
  f4 rwv;
  #pragma unroll
  for (int r=0; r<4; ++r){
    float sim = s4[r];
    float mx = sim;
    for (int k=32;k;k>>=1) mx = fmaxf(mx, __shfl_xor(mx,k));
    if (lane==0) red[wid] = mx;
    __syncthreads();
    mx = red[0];
    #pragma unroll
    for (int i=1;i<16;++i) mx = fmaxf(mx, red[i]);
    __syncthreads();
    float e = expf(sim - mx);
    float sm = e;
    for (int k=32;k;k>>=1) sm += __shfl_xor(sm,k);
    if (lane==0) red[wid] = sm;
    __syncthreads();
    sm = 0.f;
    #pragma unroll
    for (int i=0;i<16;++i) sm += red[i];
    __syncthreads();
    float m0 = p[208+r], m1 = p[212+r], m2 = p[216+r];
    float v = b4v[r]*m0 + (e/sm)*m1 + f4v[r]*m2;
    rwv[r] = v;
    srw[r][t] = v;
  }
  *(f4*)(readw_out + (base + t)*4) = rwv;
  __syncthreads();
  {
    int w = t & 63, ch = t >> 6;
    float a0=0.f,a1=0.f,a2=0.f,a3=0.f;
    for (int n = ch*64; n < ch*64+64; ++n){
      float m = mu[(base + n)*64 + w];
      a0 = fmaf(m, srw[0][n], a0);
      a1 = fmaf(m, srw[1][n], a1);
      a2 = fmaf(m, srw[2][n], a2);
      a3 = fmaf(m, srw[3][n], a3);
    }
    part[(w*4+0)*17 + ch] = a0;
    part[(w*4+1)*17 + ch] = a1;
    part[(w*4+2)*17 + ch] = a2;
    part[(w*4+3)*17 + ch] = a3;
  }
  __syncthreads();
  if (t < 256){
    const float* q = part + t*17;
    float s = 0.f;
    #pragma unroll
    for (int i=0;i<16;++i) s += q[i];
    srv[t] = s;
    rv_out[b*256 + t] = s;
  }
  __syncthreads();
  {
    int o = t & 255, q = t >> 8;
    float acc = 0.f;
    for (int k = q*64; k < q*64+64; ++k)
      acc = fmaf(srv[k], Wout[k*256 + o], acc);
    part[q*257 + o] = acc;
  }
  __syncthreads();
  if (t < 256)
    out0[b*256 + t] = bout[t] + part[0*257+t] + part[1*257+t] + part[2*257+t] + part[3*257+t];
}

extern "C" void kernel_launch(void* const* d_in, const int* in_sizes, int n_in,
                              void* d_out, int out_size, void* d_ws, size_t ws_size,
                              hipStream_t stream) {
  const float* itf   = (const float*)d_in[0];
  const float* mem   = (const float*)d_in[1];
  const float* rwts  = (const float*)d_in[2];
  const float* wwts  = (const float*)d_in[3];
  const float* usage = (const float*)d_in[4];
  const float* prec  = (const float*)d_in[5];
  const float* link  = (const float*)d_in[6];
  const float* Wout  = (const float*)d_in[7];
  const float* bout  = (const float*)d_in[8];

  float* out = (float*)d_out;
  float* o_memout   = out;                         // 8192
  float* o_mu       = out + 8192;                  // 2097152
  float* o_readw    = out + 8192 + 2097152;        // 131072
  float* o_writew   = o_readw + 131072;            // 32768
  float* o_readvec  = o_writew + 32768;            // 8192
  float* o_usage    = o_readvec + 8192;            // 32768
  float* o_precnew  = o_usage + 32768;             // 32768
  float* o_linknew  = o_precnew + 32768;           // 33554432

  float* ws = (float*)d_ws;
  float* P    = ws + WS_PARAMS;
  float* fw   = ws + WS_FW;
  float* bw   = ws + WS_BW;
  float* simr = ws + WS_SIMR;

  k_head<<<BB, 1024, 0, stream>>>(itf, mem, rwts, wwts, usage, prec,
                                  P, o_writew, o_precnew, o_usage, fw);
  k_stream<<<BB*128, 256, 0, stream>>>(link, prec, o_writew, o_linknew);
  k_fwbw<<<BB*128, 256, 0, stream>>>(link, rwts, prec, o_writew, mem, P,
                                     fw, bw, o_mu, simr);
  k_tail<<<BB, 1024, 0, stream>>>(simr, fw, bw, P, o_mu, Wout, bout,
                                  o_readw, o_readvec, o_memout);
}

// Round 28
// 118.657 us; speedup vs baseline: 1.2897x; 1.2897x over previous
//
#include <hip/hip_runtime.h>
#include <hip/hip_bf16.h>

#define BB 32
#define NN 1024
#define WW 64
#define RR 4
#define IFD 471
#define OUTD 256
#define EPS 1e-6f

typedef float f4 __attribute__((ext_vector_type(4)));

// ---------- ws layout (floats) ----------
#define WS_PARAMS 0
#define WS_SIMW   16384
#define WS_SIMR   49152
#define WS_FW     180224
#define WS_BW     311296

// params per-batch layout:
// 0:write_key[64] 64:write_vec[64] 128:erase[64] 192:free[4] 196:rstr[4]
// 200:wstr 201:wg 202:ag 203:key_norm 204:rk_norm[4] 208:mode[3][4]
// 224:read_keys[w][r] (256)

__device__ __forceinline__ float sigmoidf_(float x){ return 1.f/(1.f+expf(-x)); }
__device__ __forceinline__ float softplusf_(float x){ return fmaxf(x,0.f)+log1pf(expf(-fabsf(x))); }

// fused head: parse + usage/simw + sort/alloc + write softmax + write_w +
// precedence_new, one block per batch. Also zeros fw/bw accumulators.
__global__ __launch_bounds__(1024) void k_head(
    const float* __restrict__ itf, const float* __restrict__ mem,
    const float* __restrict__ rwts, const float* __restrict__ wwts,
    const float* __restrict__ usage_in, const float* __restrict__ prec,
    float* __restrict__ P, float* __restrict__ write_w_out,
    float* __restrict__ prec_new_out, float* __restrict__ usage_out,
    float* __restrict__ fwbw_zero){
  __shared__ float sp[512];
  __shared__ float su[1024], sv[1024], sred[1024], ssimw[1024];
  __shared__ int sidx[1024];
  int t = threadIdx.x, b = blockIdx.x;
  int lane = t & 63, wg = t >> 6;
  {
    float* z = fwbw_zero + b*8192;
    #pragma unroll
    for (int i=0;i<8;++i) z[i*1024 + t] = 0.f;
  }
  const float* x = itf + b*IFD;
  if (t < 64){
    sp[t]      = x[t];
    sp[64+t]   = x[64+t];
    sp[128+t]  = sigmoidf_(x[128+t]);
    float wk = x[t];
    float k2 = wk*wk;
    for (int m=32;m;m>>=1) k2 += __shfl_xor(k2, m);
    if (t == 0) sp[203] = sqrtf(k2);
  }
  if (t < 4){
    sp[192+t] = sigmoidf_(x[192+t]);
    sp[196+t] = 1.f + softplusf_(x[196+t]);
  }
  if (t == 0){
    sp[200] = 1.f + softplusf_(x[200]);
    sp[201] = sigmoidf_(x[201]);
    sp[202] = sigmoidf_(x[202]);
  }
  if (t < 256){
    int w = t & 63, r = t >> 6;
    float rk = x[203 + r*64 + w];
    sp[224 + w*4 + r] = rk;
    float s2 = rk*rk;
    for (int m=32;m;m>>=1) s2 += __shfl_xor(s2, m);
    if (w == 0) sp[204 + r] = sqrtf(s2);
  }
  if (t < 4){
    float a0=x[459+t*3+0], a1=x[459+t*3+1], a2=x[459+t*3+2];
    float mx = fmaxf(a0, fmaxf(a1,a2));
    float e0=expf(a0-mx), e1=expf(a1-mx), e2=expf(a2-mx);
    float s = e0+e1+e2;
    sp[208 + 0*4 + t] = e0/s;
    sp[208 + 1*4 + t] = e1/s;
    sp[208 + 2*4 + t] = e2/s;
  }
  __syncthreads();
  if (t < 512) P[b*512 + t] = sp[t];
  {
    const size_t base = (size_t)b*NN;
    int q = lane & 15, rs = lane >> 4;
    f4 wk4 = *(const f4*)(sp + q*4);
    float keyn = sp[203], wstr = sp[200];
    float g0=sp[192], g1=sp[193], g2=sp[194], g3=sp[195];
    #pragma unroll 4
    for (int it=0; it<16; ++it){
      int row = wg*64 + it*4 + rs;
      f4 m4 = *(const f4*)(mem + (base+row)*64 + q*4);
      float s2 = m4.x*m4.x + m4.y*m4.y + m4.z*m4.z + m4.w*m4.w;
      float sd = m4.x*wk4.x + m4.y*wk4.y + m4.z*wk4.z + m4.w*wk4.w;
      s2 += __shfl_xor(s2,1); sd += __shfl_xor(sd,1);
      s2 += __shfl_xor(s2,2); sd += __shfl_xor(sd,2);
      s2 += __shfl_xor(s2,4); sd += __shfl_xor(sd,4);
      s2 += __shfl_xor(s2,8); sd += __shfl_xor(sd,8);
      if (q == 0){
        ssimw[row] = sd / (sqrtf(s2)*keyn + EPS) * wstr;
        f4 r4 = *(const f4*)(rwts + (base+row)*4);
        float ret = (1.f-g0*r4.x)*(1.f-g1*r4.y)*(1.f-g2*r4.z)*(1.f-g3*r4.w);
        float pu = usage_in[base+row];
        float ww = wwts[base+row];
        float uo = (pu + ww - pu*ww) * ret;
        usage_out[base+row] = uo;
        su[row] = EPS + (1.f-EPS)*uo;
        sidx[row] = row;
      }
    }
  }
  __syncthreads();
  for (int k=2; k<=1024; k<<=1){
    for (int j=k>>1; j; j>>=1){
      int ixj = t ^ j;
      if (ixj > t){
        float a = su[t], c = su[ixj];
        int ia = sidx[t], ic = sidx[ixj];
        bool up = ((t & k) == 0);
        bool gt = (a > c) || (a == c && ia > ic);
        if (gt == up){ su[t]=c; su[ixj]=a; sidx[t]=ic; sidx[ixj]=ia; }
      }
      __syncthreads();
    }
  }
  sv[t] = su[t];
  __syncthreads();
  for (int off=1; off<1024; off<<=1){
    float y = (t >= off) ? su[t-off] : 1.f;
    __syncthreads();
    su[t] *= y;
    __syncthreads();
  }
  float excl = (t == 0) ? 1.f : su[t-1];
  float alloc_sorted = (1.f - sv[t]) * excl;
  sred[sidx[t]] = alloc_sorted;
  __syncthreads();
  float alloc = sred[t];
  float sim = ssimw[t];
  sv[t] = sim; __syncthreads();
  for (int s=512; s; s>>=1){ if (t<s) sv[t] = fmaxf(sv[t], sv[t+s]); __syncthreads(); }
  float mx = sv[0]; __syncthreads();
  float e = expf(sim - mx);
  sv[t] = e; __syncthreads();
  for (int s=512; s; s>>=1){ if (t<s) sv[t] += sv[t+s]; __syncthreads(); }
  float wa = e / sv[0];
  float wg_ = sp[201], ag = sp[202];
  float ww = wg_ * ((1.f-ag)*wa + ag*alloc);
  write_w_out[b*NN + t] = ww;
  __syncthreads();
  sv[t] = ww; __syncthreads();
  for (int s=512; s; s>>=1){ if (t<s) sv[t] += sv[t+s]; __syncthreads(); }
  float S = sv[0];
  prec_new_out[b*NN + t] = (1.f - S)*prec[b*NN + t] + ww;
}

// link_new + fused fw/bw + distributed memupd (8 rows/block).
// 128x64 tile per block (champion structure, measured 118.7/118.8 us total).
// Cached link load, NT link_new store, XCD swizzle. LDS-staged reductions;
// coalesced atomics.
__global__ __launch_bounds__(256) void k_link(const float* __restrict__ link,
    const float* __restrict__ rwts, const float* __restrict__ prec,
    const float* __restrict__ write_w, const float* __restrict__ mem,
    const float* __restrict__ P, float* __restrict__ link_new,
    float* __restrict__ fw, float* __restrict__ bw,
    float* __restrict__ mu_out, float* __restrict__ simr){
  __shared__ float red[4352];           // bw stage: (r*64 + col_local)*17 + ty
  __shared__ float sfw[512];            // fw stage: row_local*4 + r
  int t = threadIdx.x;
  int tx = t & 15, ty = t >> 4;
  int h = blockIdx.x;
  int lb = (h & 7)*512 + (h >> 3);      // XCD swizzle (4096 = 8 x 512, bijective)
  int b  = lb >> 7;
  int rt = (lb >> 4) & 7;
  int ct = lb & 15;
  int row0 = rt*128 + ty*8;
  int col0 = ct*64 + tx*4;
  const size_t base = (size_t)b*NN;
  const size_t lbb  = (size_t)b*NN*NN;
  f4 wj = *(const f4*)(write_w + base + col0);
  f4 pj = *(const f4*)(prec + base + col0);
  f4 rj0 = *(const f4*)(rwts + (base + col0+0)*4);
  f4 rj1 = *(const f4*)(rwts + (base + col0+1)*4);
  f4 rj2 = *(const f4*)(rwts + (base + col0+2)*4);
  f4 rj3 = *(const f4*)(rwts + (base + col0+3)*4);
  float fwacc[8][4];
  float bwacc[4][4];
  #pragma unroll
  for (int a=0;a<8;++a) for (int c=0;c<4;++c) fwacc[a][c]=0.f;
  #pragma unroll
  for (int a=0;a<4;++a) for (int c=0;c<4;++c) bwacc[a][c]=0.f;
  #pragma unroll
  for (int dr=0; dr<8; ++dr){
    int i = row0 + dr;
    float wi = write_w[base + i];
    f4 ri = *(const f4*)(rwts + (base + i)*4);
    f4 L4 = *(const f4*)(link + lbb + (size_t)i*NN + col0);
    float om = 1.f - wi;
    f4 v;
    v.x = fmaf(om + wj.x, L4.x, wi*pj.x);
    v.y = fmaf(om + wj.y, L4.y, wi*pj.y);
    v.z = fmaf(om + wj.z, L4.z, wi*pj.z);
    v.w = fmaf(om + wj.w, L4.w, wi*pj.w);
    v.x = (i == col0  ) ? 0.f : v.x;
    v.y = (i == col0+1) ? 0.f : v.y;
    v.z = (i == col0+2) ? 0.f : v.z;
    v.w = (i == col0+3) ? 0.f : v.w;
    __builtin_nontemporal_store(v, (f4*)(link_new + lbb + (size_t)i*NN + col0));
    fwacc[dr][0] += v.x*rj0.x + v.y*rj1.x + v.z*rj2.x + v.w*rj3.x;
    fwacc[dr][1] += v.x*rj0.y + v.y*rj1.y + v.z*rj2.y + v.w*rj3.y;
    fwacc[dr][2] += v.x*rj0.z + v.y*rj1.z + v.z*rj2.z + v.w*rj3.z;
    fwacc[dr][3] += v.x*rj0.w + v.y*rj1.w + v.z*rj2.w + v.w*rj3.w;
    bwacc[0][0] = fmaf(v.x, ri.x, bwacc[0][0]); bwacc[0][1] = fmaf(v.x, ri.y, bwacc[0][1]);
    bwacc[0][2] = fmaf(v.x, ri.z, bwacc[0][2]); bwacc[0][3] = fmaf(v.x, ri.w, bwacc[0][3]);
    bwacc[1][0] = fmaf(v.y, ri.x, bwacc[1][0]); bwacc[1][1] = fmaf(v.y, ri.y, bwacc[1][1]);
    bwacc[1][2] = fmaf(v.y, ri.z, bwacc[1][2]); bwacc[1][3] = fmaf(v.y, ri.w, bwacc[1][3]);
    bwacc[2][0] = fmaf(v.z, ri.x, bwacc[2][0]); bwacc[2][1] = fmaf(v.z, ri.y, bwacc[2][1]);
    bwacc[2][2] = fmaf(v.z, ri.z, bwacc[2][2]); bwacc[2][3] = fmaf(v.z, ri.w, bwacc[2][3]);
    bwacc[3][0] = fmaf(v.w, ri.x, bwacc[3][0]); bwacc[3][1] = fmaf(v.w, ri.y, bwacc[3][1]);
    bwacc[3][2] = fmaf(v.w, ri.z, bwacc[3][2]); bwacc[3][3] = fmaf(v.w, ri.w, bwacc[3][3]);
  }
  #pragma unroll
  for (int dr=0; dr<8; ++dr)
    #pragma unroll
    for (int r=0; r<4; ++r){
      float s = fwacc[dr][r];
      s += __shfl_xor(s,1); s += __shfl_xor(s,2);
      s += __shfl_xor(s,4); s += __shfl_xor(s,8);
      if (tx == 0) sfw[(ty*8+dr)*4 + r] = s;
    }
  #pragma unroll
  for (int dc=0; dc<4; ++dc)
    #pragma unroll
    for (int r=0; r<4; ++r)
      red[(r*64 + tx*4+dc)*17 + ty] = bwacc[dc][r];
  __syncthreads();
  // fw atomics: 512 consecutive addresses -> coalesced
  atomicAdd(&fw[(base + rt*128)*4 + t],       sfw[t]);
  atomicAdd(&fw[(base + rt*128)*4 + t + 256], sfw[t + 256]);
  // bw atomics: index = ct*256 + t -> contiguous across the wave (coalesced)
  {
    int coll = t >> 2, r = t & 3;
    const float* q = red + (r*64 + coll)*17;
    float s = 0.f;
    #pragma unroll
    for (int i=0; i<16; ++i) s += q[i];
    atomicAdd(&bw[(base + ct*64 + coll)*4 + r], s);
  }
  // distributed memory-update + read-sim: this block's 8 rows
  {
    const float* p = P + b*512;
    int slot = t >> 4;                // 0..15 (16-lane groups)
    int q = t & 15;                   // col quarter
    if (slot < 8){
      int row = rt*128 + ct*8 + slot;
      float ww = write_w[base + row];
      f4 er4 = *(const f4*)(p + 128 + q*4);
      f4 wv4 = *(const f4*)(p + 64 + q*4);
      f4 m4 = *(const f4*)(mem + (base+row)*64 + q*4);
      f4 mu;
      mu.x = m4.x*(1.f - ww*er4.x) + ww*wv4.x;
      mu.y = m4.y*(1.f - ww*er4.y) + ww*wv4.y;
      mu.z = m4.z*(1.f - ww*er4.z) + ww*wv4.z;
      mu.w = m4.w*(1.f - ww*er4.w) + ww*wv4.w;
      *(f4*)(mu_out + (base+row)*64 + q*4) = mu;
      f4 rk0 = *(const f4*)(p + 224 + (q*4+0)*4);
      f4 rk1 = *(const f4*)(p + 224 + (q*4+1)*4);
      f4 rk2 = *(const f4*)(p + 224 + (q*4+2)*4);
      f4 rk3 = *(const f4*)(p + 224 + (q*4+3)*4);
      float s2 = mu.x*mu.x + mu.y*mu.y + mu.z*mu.z + mu.w*mu.w;
      f4 d = mu.x*rk0 + mu.y*rk1 + mu.z*rk2 + mu.w*rk3;
      #pragma unroll
      for (int k=1; k<16; k<<=1){
        s2  += __shfl_xor(s2,k);
        d.x += __shfl_xor(d.x,k); d.y += __shfl_xor(d.y,k);
        d.z += __shfl_xor(d.z,k); d.w += __shfl_xor(d.w,k);
      }
      if (q == 0){
        f4 rkn = *(const f4*)(p + 204);
        f4 rst = *(const f4*)(p + 196);
        float norm = sqrtf(s2);
        f4 o;
        o.x = d.x/(norm*rkn.x+EPS)*rst.x;
        o.y = d.y/(norm*rkn.y+EPS)*rst.y;
        o.z = d.z/(norm*rkn.z+EPS)*rst.z;
        o.w = d.w/(norm*rkn.w+EPS)*rst.w;
        *(f4*)(simr + (base+row)*4) = o;
      }
    }
  }
}

// fused tail: per batch, read softmax + combine -> read_w; read_vec; GEMV out.
__global__ __launch_bounds__(1024) void k_tail(
    const float* __restrict__ simr, const float* __restrict__ fw,
    const float* __restrict__ bw, const float* __restrict__ P,
    const float* __restrict__ mu, const float* __restrict__ Wout,
    const float* __restrict__ bout,
    float* __restrict__ readw_out, float* __restrict__ rv_out,
    float* __restrict__ out0){
  __shared__ float srw[4][1024];
  __shared__ float part[4352];
  __shared__ float red[16];
  __shared__ float srv[256];
  int t = threadIdx.x, b = blockIdx.x;
  int lane = t & 63, wid = t >> 6;
  const float* p = P + b*512;
  const size_t base = (size_t)b*NN;
  f4 s4 = *(const f4*)(simr + (base + t)*4);
  f4 f4v = *(const f4*)(fw + (base + t)*4);
  f4 b4v = *(const f4*)(bw + (base + t)*4);
  f4 rwv;
  #pragma unroll
  for (int r=0; r<4; ++r){
    float sim = s4[r];
    float mx = sim;
    for (int k=32;k;k>>=1) mx = fmaxf(mx, __shfl_xor(mx,k));
    if (lane==0) red[wid] = mx;
    __syncthreads();
    mx = red[0];
    #pragma unroll
    for (int i=1;i<16;++i) mx = fmaxf(mx, red[i]);
    __syncthreads();
    float e = expf(sim - mx);
    float sm = e;
    for (int k=32;k;k>>=1) sm += __shfl_xor(sm,k);
    if (lane==0) red[wid] = sm;
    __syncthreads();
    sm = 0.f;
    #pragma unroll
    for (int i=0;i<16;++i) sm += red[i];
    __syncthreads();
    float m0 = p[208+r], m1 = p[212+r], m2 = p[216+r];
    float v = b4v[r]*m0 + (e/sm)*m1 + f4v[r]*m2;
    rwv[r] = v;
    srw[r][t] = v;
  }
  *(f4*)(readw_out + (base + t)*4) = rwv;
  __syncthreads();
  {
    int w = t & 63, ch = t >> 6;
    float a0=0.f,a1=0.f,a2=0.f,a3=0.f;
    for (int n = ch*64; n < ch*64+64; ++n){
      float m = mu[(base + n)*64 + w];
      a0 = fmaf(m, srw[0][n], a0);
      a1 = fmaf(m, srw[1][n], a1);
      a2 = fmaf(m, srw[2][n], a2);
      a3 = fmaf(m, srw[3][n], a3);
    }
    part[(w*4+0)*17 + ch] = a0;
    part[(w*4+1)*17 + ch] = a1;
    part[(w*4+2)*17 + ch] = a2;
    part[(w*4+3)*17 + ch] = a3;
  }
  __syncthreads();
  if (t < 256){
    const float* q = part + t*17;
    float s = 0.f;
    #pragma unroll
    for (int i=0;i<16;++i) s += q[i];
    srv[t] = s;
    rv_out[b*256 + t] = s;
  }
  __syncthreads();
  {
    int o = t & 255, q = t >> 8;
    float acc = 0.f;
    for (int k = q*64; k < q*64+64; ++k)
      acc = fmaf(srv[k], Wout[k*256 + o], acc);
    part[q*257 + o] = acc;
  }
  __syncthreads();
  if (t < 256)
    out0[b*256 + t] = bout[t] + part[0*257+t] + part[1*257+t] + part[2*257+t] + part[3*257+t];
}

extern "C" void kernel_launch(void* const* d_in, const int* in_sizes, int n_in,
                              void* d_out, int out_size, void* d_ws, size_t ws_size,
                              hipStream_t stream) {
  const float* itf   = (const float*)d_in[0];
  const float* mem   = (const float*)d_in[1];
  const float* rwts  = (const float*)d_in[2];
  const float* wwts  = (const float*)d_in[3];
  const float* usage = (const float*)d_in[4];
  const float* prec  = (const float*)d_in[5];
  const float* link  = (const float*)d_in[6];
  const float* Wout  = (const float*)d_in[7];
  const float* bout  = (const float*)d_in[8];

  float* out = (float*)d_out;
  float* o_memout   = out;                         // 8192
  float* o_mu       = out + 8192;                  // 2097152
  float* o_readw    = out + 8192 + 2097152;        // 131072
  float* o_writew   = o_readw + 131072;            // 32768
  float* o_readvec  = o_writew + 32768;            // 8192
  float* o_usage    = o_readvec + 8192;            // 32768
  float* o_precnew  = o_usage + 32768;             // 32768
  float* o_linknew  = o_precnew + 32768;           // 33554432

  float* ws = (float*)d_ws;
  float* P    = ws + WS_PARAMS;
  float* fw   = ws + WS_FW;
  float* bw   = ws + WS_BW;
  float* simr = ws + WS_SIMR;

  k_head<<<BB, 1024, 0, stream>>>(itf, mem, rwts, wwts, usage, prec,
                                  P, o_writew, o_precnew, o_usage, fw);
  k_link<<<BB*128, 256, 0, stream>>>(link, rwts, prec, o_writew, mem, P,
                                     o_linknew, fw, bw, o_mu, simr);
  k_tail<<<BB, 1024, 0, stream>>>(simr, fw, bw, P, o_mu, Wout, bout,
                                  o_readw, o_readvec, o_memout);
}